// Round 2
// baseline (167.553 us; speedup 1.0000x reference)
//
#include <hip/hip_runtime.h>
#include <math.h>

#define B_ 2
#define DMODEL 128
#define DIN 256
#define DSTATE 16
#define DTR 8
#define OUTC 128
#define Lseq 4096
#define NC 256          // chunks per batch
#define LC 16           // timesteps per chunk

__device__ __forceinline__ float siluf(float x){ return x / (1.f + __expf(-x)); }

// dA[s] = e1^(s+1), s=0..15, via log-depth power ladder (15 muls, depth ~4).
// Valid when A[d][s] = (s+1)*A[d][0] (true for this problem: A_log = log(arange(1..16))).
__device__ __forceinline__ void build_dA(float e1, float* dAv){
    float e2 = e1*e1, e4 = e2*e2, e8 = e4*e4;
    dAv[0]=e1;         dAv[1]=e2;         dAv[2]=e2*e1;       dAv[3]=e4;
    dAv[4]=e4*e1;      dAv[5]=e4*e2;      dAv[6]=e4*dAv[2];   dAv[7]=e8;
    dAv[8]=e8*e1;      dAv[9]=e8*e2;      dAv[10]=e8*dAv[2];  dAv[11]=e8*e4;
    dAv[12]=e8*dAv[4]; dAv[13]=e8*dAv[5]; dAv[14]=e8*dAv[6];  dAv[15]=e8*e8;
}

// fast softplus: abs error <= ~1e-7 vs log1pf(expf()) (fine: dt feeds exp(dt*A), |A|<=16)
__device__ __forceinline__ float softplusf(float a){
    return (a > 20.f) ? a : __logf(1.f + __expf(a));
}

// ---------------- Kernel AB (fused): in_proj + conv + silu + x_proj + dt_proj + scan pass 1 --------------
// Block = one 16-timestep chunk. Computes its own 3-l halo in the GEMM (3/16 redundant work) so the
// depthwise conv runs ENTIRELY out of the GEMM accumulator registers: thread t holds xin[:, t] for all
// 19 staged timesteps in acc0[]. Eliminates the 16 MB xin global round-trip and one kernel launch.
__global__ __launch_bounds__(256) void k_inconv_scan1(const float* __restrict__ x1,
        const float* __restrict__ Win,
        const float* __restrict__ convw, const float* __restrict__ convb,
        const float* __restrict__ Wx, const float* __restrict__ Wdt,
        const float* __restrict__ bdt, const float* __restrict__ Alog,
        float* __restrict__ zs, float* __restrict__ xc, float* __restrict__ dt,
        float* __restrict__ Bm, float* __restrict__ Cm, float2* __restrict__ PSw){
    __shared__ float xt[128*20];       // x tile [c][p], p=0..18 -> l = l0-3+p (pad stride 20 for b128)
    __shared__ float xcs[16*257];      // conv output [l][d]
    __shared__ float xdbl[16*40];      // x_proj output [l][40]
    int blk = blockIdx.x;              // 512 = b x 256 chunks
    int b  = blk >> 8;
    int cb = blk & 255;
    int l0 = cb << 4;
    int t  = threadIdx.x;

    // ---- phase 0: stage x tile (19 timesteps incl. 3-l causal halo, zeros at l<0) ----
    const float* xb = x1 + (size_t)b * DMODEL * Lseq;
    for (int e = t; e < 128*19; e += 256){
        int c = e / 19, p = e - c*19;
        int l = l0 - 3 + p;
        xt[c*20 + p] = (l >= 0) ? xb[(size_t)c*Lseq + l] : 0.f;
    }
    __syncthreads();

    // ---- phase 1: in_proj GEMM. thread t -> xin col t (19 p incl halo) + z col t (16 p) ----
    float acc0[19], acc1[16];
    #pragma unroll
    for (int p=0;p<19;++p) acc0[p]=0.f;
    #pragma unroll
    for (int p=0;p<16;++p) acc1[p]=0.f;
    for (int k=0;k<DMODEL;++k){
        float w0 = Win[k*512 + t];
        float w1 = Win[k*512 + t + 256];
        float xv[19];
        #pragma unroll
        for (int p=0;p<19;++p) xv[p] = xt[k*20 + p];
        #pragma unroll
        for (int p=0;p<19;++p) acc0[p] = fmaf(xv[p], w0, acc0[p]);
        #pragma unroll
        for (int p=0;p<16;++p) acc1[p] = fmaf(xv[p+3], w1, acc1[p]);
    }
    // z gate -> zs (coalesced: consecutive t -> consecutive addr)
    {
        float* zp = zs + ((size_t)(b*Lseq + l0))*DIN + t;
        #pragma unroll
        for (int p=0;p<16;++p) zp[p*DIN] = siluf(acc1[p]);
    }

    // ---- phase 2: causal depthwise conv + silu straight from acc0 registers ----
    {
        float cw0 = convw[t*4+0], cw1 = convw[t*4+1], cw2 = convw[t*4+2], cw3 = convw[t*4+3];
        float bb = convb[t];
        float* xcg = xc + ((size_t)(b*Lseq + l0))*DIN + t;
        #pragma unroll
        for (int l = 0; l < 16; ++l){
            float acc = bb;
            acc = fmaf(acc0[l],   cw0, acc);
            acc = fmaf(acc0[l+1], cw1, acc);
            acc = fmaf(acc0[l+2], cw2, acc);
            acc = fmaf(acc0[l+3], cw3, acc);
            float v = siluf(acc);
            xcs[l*257 + t] = v;
            xcg[l*DIN] = v;
        }
    }
    __syncthreads();

    // ---- phase 3: x_proj (128 active threads: 16 rows x 8 col-groups of 5) ----
    if (t < 128){
        int jg = t & 7;
        int lg = t >> 3;
        int j0 = jg * 5;
        float a0=0.f, a1=0.f, a2=0.f, a3=0.f, a4=0.f;
        const float* xrow = xcs + lg*257;
        const float* wbase = Wx + j0;
        #pragma unroll 8
        for (int d = 0; d < 256; ++d){
            float xv = xrow[d];
            const float* wr = wbase + d*40;
            a0 = fmaf(xv, wr[0], a0);
            a1 = fmaf(xv, wr[1], a1);
            a2 = fmaf(xv, wr[2], a2);
            a3 = fmaf(xv, wr[3], a3);
            a4 = fmaf(xv, wr[4], a4);
        }
        float* xo = xdbl + lg*40 + j0;
        xo[0]=a0; xo[1]=a1; xo[2]=a2; xo[3]=a3; xo[4]=a4;
    }
    __syncthreads();

    // ---- phase 4: dt_proj + softplus + fused scan pass 1 ----
    {
        float wd[DTR];
        #pragma unroll
        for (int r=0;r<DTR;++r) wd[r] = Wdt[r*DIN + t];
        float bv = bdt[t];
        float Av[16];
        {
            const float4* Ap = (const float4*)(Alog + t*DSTATE);
            #pragma unroll
            for (int q=0;q<4;++q){
                float4 a = Ap[q];
                Av[q*4]   = -__expf(a.x);
                Av[q*4+1] = -__expf(a.y);
                Av[q*4+2] = -__expf(a.z);
                Av[q*4+3] = -__expf(a.w);
            }
        }
        bool fastA = true;
        #pragma unroll
        for (int i=1;i<16;++i)
            fastA = fastA && (fabsf(Av[i] - (float)(i+1)*Av[0]) <= 1e-6f*fabsf(Av[i]));
        float P[16], S[16];
        #pragma unroll
        for (int s=0;s<16;++s){ P[s]=1.f; S[s]=0.f; }
        float* dtg = dt + ((size_t)(b*Lseq + l0))*DIN + t;
        #pragma unroll 4
        for (int l=0;l<16;++l){
            float a = bv;
            #pragma unroll
            for (int r=0;r<DTR;++r) a = fmaf(xdbl[l*40 + r], wd[r], a);
            float dtv = softplusf(a);
            dtg[l*DIN] = dtv;
            float xcv = xcs[l*257 + t];
            float dx  = dtv*xcv;
            const float4* Bv = (const float4*)&xdbl[l*40 + DTR];
            float4 B0 = Bv[0], B1 = Bv[1], B2 = Bv[2], B3 = Bv[3];
            float dAv[16];
            if (fastA){
                build_dA(__expf(dtv*Av[0]), dAv);
            } else {
                #pragma unroll
                for (int i=0;i<16;++i) dAv[i] = __expf(dtv*Av[i]);
            }
            #define ST1(i, bval) { P[i] *= dAv[i]; S[i] = fmaf(dAv[i], S[i], dx*(bval)); }
            ST1(0,B0.x) ST1(1,B0.y) ST1(2,B0.z) ST1(3,B0.w)
            ST1(4,B1.x) ST1(5,B1.y) ST1(6,B1.z) ST1(7,B1.w)
            ST1(8,B2.x) ST1(9,B2.y) ST1(10,B2.z) ST1(11,B2.w)
            ST1(12,B3.x) ST1(13,B3.y) ST1(14,B3.z) ST1(15,B3.w)
            #undef ST1
        }
        float2* ps = PSw + ((size_t)(b*NC + cb))*4096 + t*DSTATE;
        #pragma unroll
        for (int s=0;s<16;++s) ps[s] = make_float2(P[s], S[s]);
    }
    // ---- B/C extraction (16 l x 32 cols) ----
    for (int o = t; o < 512; o += 256){
        int l = o >> 5, q = o & 31;
        float v = xdbl[l*40 + DTR + q];
        size_t g = ((size_t)(b*Lseq + l0 + l))*DSTATE;
        if (q < DSTATE) Bm[g + q] = v;
        else            Cm[g + (q - DSTATE)] = v;
    }
}

// ---------------- Kernel C: pass 2, hierarchical chunk combine (affine composition is associative) -------
// 512 blocks: block = 16 channels x 16 chunk-groups of 16 chunks. Each thread composes its 16 chunks in
// registers (one PSw read total), LDS scan stitches the 16 groups, register rescan emits entry states.
__global__ __launch_bounds__(256) void k_scan2(const float2* __restrict__ PSw,
        float* __restrict__ Iw){
    __shared__ float2 gps[16][16];
    __shared__ float  ge [16][16];
    int blk = blockIdx.x;               // 512 = b x 256 channel-groups of 16
    int b  = blk >> 8;
    int r0 = (blk & 255) * 16;
    int t  = threadIdx.x;
    int rr = t & 15;                    // channel within group
    int cg = t >> 4;                    // chunk-group 0..15 (16 chunks each)
    size_t base = ((size_t)(b*NC + cg*16))*4096 + r0 + rr;
    float Pl[16], Sl[16];
    float Pa = 1.f, Sa = 0.f;
    #pragma unroll
    for (int i=0;i<16;++i){
        float2 ps = PSw[base + (size_t)i*4096];
        Pl[i] = ps.x; Sl[i] = ps.y;
        Pa = ps.x * Pa;
        Sa = fmaf(ps.x, Sa, ps.y);
    }
    gps[cg][rr] = make_float2(Pa, Sa);
    __syncthreads();
    if (t < 16){
        float H = 0.f;
        #pragma unroll
        for (int g=0; g<16; ++g){
            float2 ps = gps[g][t];
            ge[g][t] = H;
            H = fmaf(ps.x, H, ps.y);
        }
    }
    __syncthreads();
    float H = ge[cg][rr];
    #pragma unroll
    for (int i=0;i<16;++i){
        Iw[base + (size_t)i*4096] = H;
        H = fmaf(Pl[i], H, Sl[i]);
    }
}

// ---------------- Kernel D: fused scan pass 3 + out_proj + LayerNorm + NCHW store -------------------------
// 512 blocks (b x 256 chunks of 16 l), 256 threads. dA power ladder replaces 16 exps per timestep.
__global__ __launch_bounds__(256) void k_scan3out(const float* __restrict__ dt,
        const float* __restrict__ xc, const float* __restrict__ zs,
        const float* __restrict__ Bm, const float* __restrict__ Cm,
        const float* __restrict__ Alog, const float* __restrict__ Dv,
        const float* __restrict__ Iw,
        const float* __restrict__ Wout, const float* __restrict__ lng,
        const float* __restrict__ lnb, float* __restrict__ out){
    __shared__ float ysm[256*18];      // [d][l] stride 18
    __shared__ float os[128*18];       // [c][l] stride 18
    __shared__ float Bs[LC*DSTATE];    // 256
    __shared__ float Cs[LC*DSTATE];
    int blk = blockIdx.x;
    int b = blk >> 8, c = blk & 255;
    int l0 = c * LC;
    int t = threadIdx.x;               // = d in scan phase
    size_t gb = (size_t)(b*Lseq + l0);
    Bs[t] = Bm[gb*DSTATE + t];
    Cs[t] = Cm[gb*DSTATE + t];
    float Av[16];
    {
        const float4* Ap = (const float4*)(Alog + t*DSTATE);
        #pragma unroll
        for (int q=0;q<4;++q){
            float4 a = Ap[q];
            Av[q*4]   = -__expf(a.x);
            Av[q*4+1] = -__expf(a.y);
            Av[q*4+2] = -__expf(a.z);
            Av[q*4+3] = -__expf(a.w);
        }
    }
    bool fastA = true;
    #pragma unroll
    for (int i=1;i<16;++i)
        fastA = fastA && (fabsf(Av[i] - (float)(i+1)*Av[0]) <= 1e-6f*fabsf(Av[i]));
    float h[16];
    {
        const float4* Ip = (const float4*)(Iw + ((size_t)(b*NC + c))*4096 + t*DSTATE);
        #pragma unroll
        for (int q=0;q<4;++q){
            float4 v = Ip[q];
            h[q*4]=v.x; h[q*4+1]=v.y; h[q*4+2]=v.z; h[q*4+3]=v.w;
        }
    }
    float Dd = Dv[t];
    // register-stage all 48 loads (independent -> single latency window)
    float dtv[LC], xcv[LC], zvv[LC];
    {
        const float* dtp = dt + gb*DIN + t;
        const float* xcp = xc + gb*DIN + t;
        const float* zsp = zs + gb*DIN + t;
        #pragma unroll
        for (int l=0;l<LC;++l){
            dtv[l] = dtp[l*DIN];
            xcv[l] = xcp[l*DIN];
            zvv[l] = zsp[l*DIN];
        }
    }
    __syncthreads();
    #pragma unroll
    for (int l=0;l<LC;++l){
        float dtl = dtv[l];
        float dx  = dtl*xcv[l];
        const float4* Bv = (const float4*)&Bs[l*DSTATE];
        const float4* Cv = (const float4*)&Cs[l*DSTATE];
        float4 B0 = Bv[0], B1 = Bv[1], B2 = Bv[2], B3 = Bv[3];
        float4 C0 = Cv[0], C1 = Cv[1], C2 = Cv[2], C3 = Cv[3];
        float dAv[16];
        if (fastA){
            build_dA(__expf(dtl*Av[0]), dAv);
        } else {
            #pragma unroll
            for (int i=0;i<16;++i) dAv[i] = __expf(dtl*Av[i]);
        }
        float y = 0.f;
        #define ST3(i, bval, cval) { h[i] = fmaf(dAv[i], h[i], dx*(bval)); y = fmaf(h[i], (cval), y); }
        ST3(0,B0.x,C0.x) ST3(1,B0.y,C0.y) ST3(2,B0.z,C0.z) ST3(3,B0.w,C0.w)
        ST3(4,B1.x,C1.x) ST3(5,B1.y,C1.y) ST3(6,B1.z,C1.z) ST3(7,B1.w,C1.w)
        ST3(8,B2.x,C2.x) ST3(9,B2.y,C2.y) ST3(10,B2.z,C2.z) ST3(11,B2.w,C2.w)
        ST3(12,B3.x,C3.x) ST3(13,B3.y,C3.y) ST3(14,B3.z,C3.z) ST3(15,B3.w,C3.w)
        #undef ST3
        ysm[t*18 + l] = (y + Dd*xcv[l])*zvv[l];
    }
    __syncthreads();
    // ---- out_proj: 16l x 128c tile. lg=t>>5 -> l {lg*2, lg*2+1}; cg=t&31 -> 4 c.
    int lg = t >> 5, cg = t & 31;
    int l0t = lg*2, c0 = cg*4;
    float acc[2][4];
    #pragma unroll
    for (int i=0;i<2;++i)
        #pragma unroll
        for (int j=0;j<4;++j) acc[i][j]=0.f;
    #pragma unroll 4
    for (int k=0;k<DIN;++k){
        float2 yv = *(const float2*)&ysm[k*18 + l0t];
        float4 wv = *(const float4*)&Wout[k*OUTC + c0];
        acc[0][0]=fmaf(yv.x,wv.x,acc[0][0]); acc[0][1]=fmaf(yv.x,wv.y,acc[0][1]);
        acc[0][2]=fmaf(yv.x,wv.z,acc[0][2]); acc[0][3]=fmaf(yv.x,wv.w,acc[0][3]);
        acc[1][0]=fmaf(yv.y,wv.x,acc[1][0]); acc[1][1]=fmaf(yv.y,wv.y,acc[1][1]);
        acc[1][2]=fmaf(yv.y,wv.z,acc[1][2]); acc[1][3]=fmaf(yv.y,wv.w,acc[1][3]);
    }
    // LayerNorm over c: reduce across the 32 lanes sharing this l (xor<=16 stays in half-wave)
    float4 gm = *(const float4*)&lng[c0];
    float4 bt = *(const float4*)&lnb[c0];
    #pragma unroll
    for (int i=0;i<2;++i){
        float rs = acc[i][0]+acc[i][1]+acc[i][2]+acc[i][3];
        #pragma unroll
        for (int m=16;m>0;m>>=1) rs += __shfl_xor(rs, m, 64);
        float mu = rs * (1.f/128.f);
        float d0 = acc[i][0]-mu, d1 = acc[i][1]-mu, d2 = acc[i][2]-mu, d3 = acc[i][3]-mu;
        float sq = d0*d0+d1*d1+d2*d2+d3*d3;
        #pragma unroll
        for (int m=16;m>0;m>>=1) sq += __shfl_xor(sq, m, 64);
        float rstd = rsqrtf(sq * (1.f/128.f) + 1e-5f);
        int lidx = l0t + i;
        os[(c0+0)*18 + lidx] = d0*rstd*gm.x + bt.x;
        os[(c0+1)*18 + lidx] = d1*rstd*gm.y + bt.y;
        os[(c0+2)*18 + lidx] = d2*rstd*gm.z + bt.z;
        os[(c0+3)*18 + lidx] = d3*rstd*gm.w + bt.w;
    }
    __syncthreads();
    // store: cc = t>>1 (0..127), sel = t&1 -> 8 consecutive l = 32B per lane; full 64B lines per c
    {
        int cc = t >> 1, sel = t & 1;
        const float* ip = &os[cc*18 + sel*8];
        float2 a0 = *(const float2*)(ip);
        float2 a1 = *(const float2*)(ip+2);
        float2 a2 = *(const float2*)(ip+4);
        float2 a3 = *(const float2*)(ip+6);
        float* op = out + ((size_t)(b*OUTC + cc))*Lseq + l0 + sel*8;
        *(float4*)(op)   = make_float4(a0.x,a0.y,a1.x,a1.y);
        *(float4*)(op+4) = make_float4(a2.x,a2.y,a3.x,a3.y);
    }
}

extern "C" void kernel_launch(void* const* d_in, const int* in_sizes, int n_in,
                              void* d_out, int out_size, void* d_ws, size_t ws_size,
                              hipStream_t stream) {
    const float* x1    = (const float*)d_in[0];
    const float* Win   = (const float*)d_in[1];
    const float* convw = (const float*)d_in[2];
    const float* convb = (const float*)d_in[3];
    const float* Wx    = (const float*)d_in[4];
    const float* Wdt   = (const float*)d_in[5];
    const float* bdt   = (const float*)d_in[6];
    const float* Alog  = (const float*)d_in[7];
    const float* Dv    = (const float*)d_in[8];
    const float* Wout  = (const float*)d_in[9];
    const float* lng   = (const float*)d_in[10];
    const float* lnb   = (const float*)d_in[11];
    float* out = (float*)d_out;

    float* ws  = (float*)d_ws;
    float* Iw  = ws;                        // 2,097,152 floats (entry states, written by scan2)
    float* zs  = Iw  + 2097152;             // 2,097,152
    float* xc  = zs  + 2097152;             // 2,097,152
    float* dt  = xc  + 2097152;             // 2,097,152
    float* Bm  = dt  + 2097152;             //   131,072
    float* Cm  = Bm  + 131072;              //   131,072
    float2* PSw = (float2*)(Cm + 131072);   // 2,097,152 float2 (~51.4 MB total, same as before)

    k_inconv_scan1<<<512, 256, 0, stream>>>(x1, Win, convw, convb, Wx, Wdt, bdt, Alog,
                                            zs, xc, dt, Bm, Cm, PSw);
    k_scan2       <<<512, 256, 0, stream>>>(PSw, Iw);
    k_scan3out    <<<512, 256, 0, stream>>>(dt, xc, zs, Bm, Cm, Alog, Dv, Iw,
                                            Wout, lng, lnb, out);
}